// Round 15
// baseline (83.384 us; speedup 1.0000x reference)
//
#include <hip/hip_runtime.h>
#include <hip/hip_bf16.h>

#define CIN  64
#define HH   128
#define WW   128
#define COUT 128
#define HO   126
#define WO   126
#define NB   32
#define HW   (HH * WW)

typedef __bf16 bf16x8 __attribute__((ext_vector_type(8)));
typedef float f32x16 __attribute__((ext_vector_type(16)));

// ws2 granule layout: [step(18)=(s,h)][kg(4)][cout(128)] 16B granules
// granule(step,kg,cout)[j] = bf16(w[cout][ci = 32h + 8kg + j][s])
__global__ void wreorder_3556(const float* __restrict__ w, unsigned short* __restrict__ ws2) {
    int e = blockIdx.x * 256 + threadIdx.x;      // 0..73727
    if (e >= 73728) return;
    int j = e & 7, cout = (e >> 3) & 127, kg = (e >> 10) & 3, h = (e >> 12) & 1, s = e >> 13;
    __bf16 v = (__bf16)w[cout * 576 + (h * 32 + kg * 8 + j) * 9 + s];
    ws2[e] = __builtin_bit_cast(unsigned short, v);
}

// LDS: xs [row(4)][cg(8)][col(130)] 16B granules (ci-major) @0 = 66560 | pmin[2][128] f32
#define XS_OFF  0
#define PM_OFF  66560
#define SMEM_BYTES (66560 + 2 * 128 * 4)   // 67584 -> 2 blocks/CU

__device__ __forceinline__ unsigned lds_addr(const void* p) {
    return (unsigned)(unsigned long long)(const __attribute__((address_space(3))) unsigned char*)p;
}
template<int OFF>
__device__ __forceinline__ bf16x8 ds_read128(unsigned base) {
    bf16x8 d;
    asm volatile("ds_read_b128 %0, %1 offset:%c2" : "=v"(d) : "v"(base), "i"(OFF));
    return d;
}
template<int OFF>
__device__ __forceinline__ bf16x8 glob_load128(const unsigned char* sbase, unsigned voff) {
    bf16x8 d;
    asm volatile("global_load_dwordx4 %0, %1, %2 offset:%c3"
                 : "=v"(d) : "v"(voff), "s"(sbase), "i"(OFF));
    return d;
}

#define MFMA_(a, b, c) __builtin_amdgcn_mfma_f32_32x32x16_bf16((a), (b), (c), 0, 0, 0)

// step T: s = T>>1, h = T&1; kh = s/3, kw = s%3
#define S_(T)  ((T) >> 1)
#define H_(T)  ((T) & 1)
#define KH_(T) (S_(T) / 3)
#define KW_(T) (S_(T) % 3)
#define IMMB(T, KS, N) (KH_(T) * 16640 + (H_(T) * 4 + (KS) * 2) * 2080 + ((N) * 32 + KW_(T)) * 16)

template<bool USE_WS>
__global__ __launch_bounds__(256, 2)
void conv_min_tanh_3556(const float* __restrict__ x, const float* __restrict__ w,
                        const float* __restrict__ bias,
                        const unsigned char* __restrict__ wsr_b,
                        float* __restrict__ out) {
    __shared__ __align__(16) unsigned char smem[SMEM_BYTES];
    float* pmin = (float*)(smem + PM_OFF);

    // XCD-chunked bijective swizzle (2016 = 8 * 252)
    const int bid = blockIdx.x;
    const int blk = (bid & 7) * 252 + (bid >> 3);
    const int b   = blk / 63;
    const int R   = (blk - b * 63) * 2;      // output rows R, R+1; input rows R..R+3

    const int tid  = threadIdx.x;
    const int lane = tid & 63;
    const int wid  = tid >> 6;               // 0..3
    const int l31 = lane & 31;
    const int l5  = lane >> 5;
    const int waveC = wid & 1;               // col half (0/1)
    const int waveR = wid >> 1;              // output row within pair (0/1)

    // ---- stage x rows R..R+3 into xs[row][cg][col] granules (conflict-free, R13 pattern)
    {
        const int cg = tid >> 5, c0 = tid & 31;
        const float* xb = x + (size_t)b * CIN * HW + (size_t)(cg * 8) * HW + (size_t)R * WW + c0;
        #pragma unroll
        for (int row = 0; row < 4; ++row) {
            #pragma unroll
            for (int i = 0; i < 4; ++i) {
                union { unsigned short us[8]; int4 i4; } p;
                #pragma unroll
                for (int j = 0; j < 8; ++j) {
                    __bf16 t = (__bf16)xb[(size_t)j * HW + (size_t)row * WW + i * 32];
                    p.us[j] = __builtin_bit_cast(unsigned short, t);
                }
                *(int4*)(smem + XS_OFF + ((row * 8 + cg) * 130 + i * 32 + c0) * 16) = p.i4;
            }
        }
        if (tid < 64) {   // zero-pad cols 128,129 for all 4 rows
            int row = tid >> 4, cgz = (tid >> 1) & 7, colz = 128 + (tid & 1);
            int4 z = {0, 0, 0, 0};
            *(int4*)(smem + XS_OFF + ((row * 8 + cgz) * 130 + colz) * 16) = z;
        }
    }
    __syncthreads();

    f32x16 acc[4][2] = {};   // [m][n] : 128 cout x 64 col

    if constexpr (USE_WS) {
        const unsigned baseB = lds_addr(smem) +
            (unsigned)(waveR * 16640 + l5 * 2080 + (waveC * 64 + l31) * 16);
        const unsigned voffA = (unsigned)(l5 * 2048 + l31 * 16);

        bf16x8 A2[2][2][4];   // [slot(2)][ks][m]  64 VGPR
        bf16x8 B2[2][2][2];   // [slot(2)][ks][n]  32 VGPR

        #define PRELA(T) do {                                                                 \
            const unsigned _va = voffA + (T) * 8192u, _vb = _va + 4096u;                      \
            A2[(T) & 1][0][0] = glob_load128<0>(wsr_b, _va);                                  \
            A2[(T) & 1][0][1] = glob_load128<512>(wsr_b, _va);                                \
            A2[(T) & 1][0][2] = glob_load128<1024>(wsr_b, _va);                               \
            A2[(T) & 1][0][3] = glob_load128<1536>(wsr_b, _va);                               \
            A2[(T) & 1][1][0] = glob_load128<0>(wsr_b, _vb);                                  \
            A2[(T) & 1][1][1] = glob_load128<512>(wsr_b, _vb);                                \
            A2[(T) & 1][1][2] = glob_load128<1024>(wsr_b, _vb);                               \
            A2[(T) & 1][1][3] = glob_load128<1536>(wsr_b, _vb); } while (0)

        #define PRELB(T) do {                                                                 \
            B2[(T) & 1][0][0] = ds_read128<IMMB(T,0,0)>(baseB);                               \
            B2[(T) & 1][0][1] = ds_read128<IMMB(T,0,1)>(baseB);                               \
            B2[(T) & 1][1][0] = ds_read128<IMMB(T,1,0)>(baseB);                               \
            B2[(T) & 1][1][1] = ds_read128<IMMB(T,1,1)>(baseB); } while (0)

        #define KSTEP(T) do {                                                                 \
            if ((T) <= 16) asm volatile("s_waitcnt lgkmcnt(4) vmcnt(8)" ::: "memory");        \
            else           asm volatile("s_waitcnt lgkmcnt(0) vmcnt(0)" ::: "memory");        \
            __builtin_amdgcn_sched_barrier(0);                                                \
            __builtin_amdgcn_s_setprio(1);                                                    \
            { const int _q = (T) & 1;                                                         \
              acc[0][0] = MFMA_(A2[_q][0][0], B2[_q][0][0], acc[0][0]);                       \
              acc[0][1] = MFMA_(A2[_q][0][0], B2[_q][0][1], acc[0][1]);                       \
              acc[1][0] = MFMA_(A2[_q][0][1], B2[_q][0][0], acc[1][0]);                       \
              acc[1][1] = MFMA_(A2[_q][0][1], B2[_q][0][1], acc[1][1]);                       \
              acc[2][0] = MFMA_(A2[_q][0][2], B2[_q][0][0], acc[2][0]);                       \
              acc[2][1] = MFMA_(A2[_q][0][2], B2[_q][0][1], acc[2][1]);                       \
              acc[3][0] = MFMA_(A2[_q][0][3], B2[_q][0][0], acc[3][0]);                       \
              acc[3][1] = MFMA_(A2[_q][0][3], B2[_q][0][1], acc[3][1]);                       \
              acc[0][0] = MFMA_(A2[_q][1][0], B2[_q][1][0], acc[0][0]);                       \
              acc[0][1] = MFMA_(A2[_q][1][0], B2[_q][1][1], acc[0][1]);                       \
              acc[1][0] = MFMA_(A2[_q][1][1], B2[_q][1][0], acc[1][0]);                       \
              acc[1][1] = MFMA_(A2[_q][1][1], B2[_q][1][1], acc[1][1]);                       \
              acc[2][0] = MFMA_(A2[_q][1][2], B2[_q][1][0], acc[2][0]);                       \
              acc[2][1] = MFMA_(A2[_q][1][2], B2[_q][1][1], acc[2][1]);                       \
              acc[3][0] = MFMA_(A2[_q][1][3], B2[_q][1][0], acc[3][0]);                       \
              acc[3][1] = MFMA_(A2[_q][1][3], B2[_q][1][1], acc[3][1]); }                     \
            __builtin_amdgcn_s_setprio(0);                                                    \
            __builtin_amdgcn_sched_barrier(0);                                                \
            if ((T) + 2 <= 17) { PRELB((T) + 2); PRELA((T) + 2); }                            \
        } while (0)

        PRELA(0); PRELB(0); PRELA(1); PRELB(1);

        KSTEP(0);  KSTEP(1);  KSTEP(2);  KSTEP(3);  KSTEP(4);  KSTEP(5);
        KSTEP(6);  KSTEP(7);  KSTEP(8);  KSTEP(9);  KSTEP(10); KSTEP(11);
        KSTEP(12); KSTEP(13); KSTEP(14); KSTEP(15); KSTEP(16); KSTEP(17);

        asm volatile("s_waitcnt lgkmcnt(0) vmcnt(0)" ::: "memory");
        __builtin_amdgcn_sched_barrier(0);
    } else {
        // fallback: plain loop straight from w
        #pragma unroll
        for (int step = 0; step < 18; ++step) {
            const int s = step >> 1, h = step & 1;
            const int kh = s / 3, kw = s % 3;
            bf16x8 A[2][4], B[2][2];
            #pragma unroll
            for (int ks = 0; ks < 2; ++ks) {
                #pragma unroll
                for (int m = 0; m < 4; ++m)
                    #pragma unroll
                    for (int j = 0; j < 8; ++j)
                        A[ks][m][j] = (__bf16)w[(m * 32 + l31) * 576 +
                                                (h * 32 + (2 * ks + l5) * 8 + j) * 9 + s];
                const int rowOff = ((waveR + kh) * 8 + h * 4 + ks * 2 + l5) * 2080;
                #pragma unroll
                for (int n = 0; n < 2; ++n)
                    B[ks][n] = *(const bf16x8*)(smem + XS_OFF + rowOff +
                                                (waveC * 64 + n * 32 + l31 + kw) * 16);
            }
            #pragma unroll
            for (int ks = 0; ks < 2; ++ks)
                #pragma unroll
                for (int m = 0; m < 4; ++m)
                    #pragma unroll
                    for (int n = 0; n < 2; ++n)
                        acc[m][n] = MFMA_(A[ks][m], B[ks][n], acc[m][n]);
        }
    }

    // ---- epilogue: +bias, min over ALL 128 couts in-wave, tanh(tanh)
    float pm[2] = {1e30f, 1e30f};
    #pragma unroll
    for (int m = 0; m < 4; ++m) {
        #pragma unroll
        for (int r = 0; r < 16; ++r) {
            float bv = bias[m * 32 + (r & 3) + 8 * (r >> 2) + 4 * l5];
            pm[0] = fminf(pm[0], acc[m][0][r] + bv);
            pm[1] = fminf(pm[1], acc[m][1][r] + bv);
        }
    }
    pm[0] = fminf(pm[0], __shfl_xor(pm[0], 32, 64));
    pm[1] = fminf(pm[1], __shfl_xor(pm[1], 32, 64));
    if (l5 == 0) {
        pmin[waveR * 128 + waveC * 64 + l31]      = pm[0];
        pmin[waveR * 128 + waveC * 64 + 32 + l31] = pm[1];
    }
    __syncthreads();

    {
        const int hh  = tid >> 7;            // 0..1
        const int col = tid & 127;
        if (col < WO) {
            float v = pmin[hh * 128 + col];
            v = tanhf(tanhf(v));
            out[((size_t)b * HO + R + hh) * WO + col] = v;
        }
    }
}

extern "C" void kernel_launch(void* const* d_in, const int* in_sizes, int n_in,
                              void* d_out, int out_size, void* d_ws, size_t ws_size,
                              hipStream_t stream) {
    const float* x    = (const float*)d_in[0];
    const float* w    = (const float*)d_in[1];
    const float* bias = (const float*)d_in[2];
    float* out = (float*)d_out;

    const size_t ws_needed = (size_t)18 * 4 * 128 * 16;   // 147456 B
    if (ws_size >= ws_needed) {
        unsigned short* wsb = (unsigned short*)d_ws;
        wreorder_3556<<<288, 256, 0, stream>>>(w, wsb);
        conv_min_tanh_3556<true><<<NB * 63, 256, 0, stream>>>(x, w, bias, (const unsigned char*)wsb, out);
    } else {
        conv_min_tanh_3556<false><<<NB * 63, 256, 0, stream>>>(x, w, bias, nullptr, out);
    }
}